// Round 17
// baseline (880.599 us; speedup 1.0000x reference)
//
#include <hip/hip_runtime.h>

// B=4,H=16,S=2048,D=64 fp32 attention, bf16-MFMA flash kernel, round 23
// (= round 22 resubmitted verbatim; r22 hit GPUAcquisitionTimeout before
//  executing -- no counters, nothing to update on).
// r17 post-mortem: 8-wave/QT=256 geometry WIN, 118 -> 108us (prediction
// matched: per-CU staging overhead was on critical path). Still nothing
// saturated (Mfma 26.5 / VALU 33.6 / HBM 11%) -> latency-bound at 16
// waves/CU, and wave count was PINNED by the decomposition (S*BH/32).
// This round: IN-BLOCK SPLIT-K x2 -> 32 waves/CU (100% occupancy).
//   * 1024-thread blocks (16 waves), grid 512 (2 blocks/CU).
//   * waves 0-7 (kh=0): keys 0..1023; waves 8-15 (kh=1): keys 1024..2047,
//     SAME 256 q-rows. Each half = r17 inner loop verbatim on its own
//     LDS tile set Ks[kh]/Vt[kh] (72 KB/block; 144 KB/CU <= 160).
//   * combine is EXACT (no max-subtraction anywhere): o_tot = o0+o1 halves,
//     l_tot = l0+l1. Done in-LDS at epilogue: Ks/Vt regions reused as
//     exchange buffers (lane-minor layout, conflict-free); waves 8-15
//     write partials, waves 0-7 add, normalize, store. No d_ws, no
//     second kernel, no coop launch.
//   * __launch_bounds__(1024,8) pins VGPR<=64 (r17 compiled at exactly 64);
//     spill signature (WRITE balloon + dur collapse) = bound failed.
// Layouts (m74/m101-verified): A/B frag [i=lane&31][k=(lane>>5)*8+j],
// C/D: col=lane&31, row=(reg&3)+8*(reg>>2)+4*(lane>>5).
// permlane32_swap recipe (m214v22): A=swap(pk2(p0,p1),pk2(p4,p5)),
// B=swap(pk2(p2,p3),pk2(p6,p7)), frag={A0,B0,A1,B1}.

#define S_LEN 2048
#define D_LEN 64
#define QT    256
#define TK    64
#define THREADS 1024
#define KSTR  72    // halfwords per LDS row (144 B): 16B-aligned, conflict-free
#define NTH   16    // K-tiles per half (1024 keys / TK)
#define HKEYS 1024  // keys per half

typedef __attribute__((ext_vector_type(8)))  short bf16x8;
typedef __attribute__((ext_vector_type(16))) float f32x16;

#if __has_builtin(__builtin_amdgcn_exp2f)
#define FAST_EXP2(x) __builtin_amdgcn_exp2f(x)
#else
#define FAST_EXP2(x) __expf((x) * 0.69314718055994531f)
#endif

// HW packed f32->bf16: D[15:0]=bf16(a), D[31:16]=bf16(b). One VALU op.
__device__ __forceinline__ unsigned pk2(float a, float b) {
    unsigned r;
    asm("v_cvt_pk_bf16_f32 %0, %1, %2" : "=v"(r) : "v"(a), "v"(b));
    return r;
}

// v_permlane32_swap_b32 a, b: swaps a's upper-32-lane half with b's
// lower-32-lane half; both outputs are usable fragment words.
__device__ __forceinline__ void pl32(unsigned& a, unsigned& b) {
    asm("v_permlane32_swap_b32 %0, %1" : "+v"(a), "+v"(b));
}

__global__ __launch_bounds__(THREADS, 8)
void attn_mfma32(const float* __restrict__ qg,
                 const float* __restrict__ kg,
                 const float* __restrict__ vg,
                 float* __restrict__ og)
{
    // [half][dbuf] tile sets; 36,864 B each array, 73,728 B total.
    __shared__ alignas(16) unsigned short Ks[2][2][TK * KSTR];    // [key][d]
    __shared__ alignas(16) unsigned short Vt[2][2][D_LEN * KSTR]; // [d][key]

    const int tid   = threadIdx.x;
    const int w     = tid >> 6;       // 0..15
    const int kh    = w >> 3;         // K-half: 0 or 1
    const int wl    = w & 7;          // wave index within half
    const int tid_h = tid & 511;      // thread index within half
    const int lane  = tid & 63;
    const int q31   = lane & 31;
    const int hi    = lane >> 5;

    // XCD swizzle (512 blocks, bijective): all 8 q-blocks of one bh on one XCD.
    const int swz   = (blockIdx.x & 7) * 64 + (blockIdx.x >> 3);
    const int bh    = swz >> 3;
    const int qblk  = swz & 7;
    const int qrow0 = qblk * QT + wl * 32;

    const float* kbase = kg + (size_t)bh * S_LEN * D_LEN + (size_t)kh * HKEYS * D_LEN;
    const float* vbase = vg + (size_t)bh * S_LEN * D_LEN + (size_t)kh * HKEYS * D_LEN;

    // ---- Q fragments: B-operand, lane holds Q[qrow0+q31][kf*16+hi*8+j] ----
    // (both halves load the same rows -- duplicated once, negligible)
    const float c = 0.125f * 1.4426950408889634f;
    bf16x8 qf[4];
    {
        const float* qp = qg + ((size_t)bh * S_LEN + qrow0 + q31) * D_LEN + hi * 8;
#pragma unroll
        for (int kf = 0; kf < 4; ++kf) {
            float4 a = ((const float4*)(qp + kf * 16))[0];
            float4 b = ((const float4*)(qp + kf * 16))[1];
            uint4 u = make_uint4(pk2(a.x * c, a.y * c), pk2(a.z * c, a.w * c),
                                 pk2(b.x * c, b.y * c), pk2(b.z * c, b.w * c));
            qf[kf] = __builtin_bit_cast(bf16x8, u);
        }
    }

    f32x16 o0, o1;
#pragma unroll
    for (int i = 0; i < 16; ++i) { o0[i] = 0.f; o1[i] = 0.f; }
    float lsum = 0.f;

    // ---- staging assignment (512 threads per half stage that half's tile) --
    // K: thread -> key=tid_h>>3 (0..63), 8-d chunk sc=tid_h&7; 2 float4.
    const int skey = tid_h >> 3;
    const int sc   = tid_h & 7;
    const float4* kptr = (const float4*)kbase + (size_t)skey * 16 + sc * 2;
    // V: lane = d, wave wl covers keys wl*8..wl*8+7; scalar coalesced loads.
    const float* vptr = vbase + (size_t)(wl * 8) * D_LEN + lane;

    float4 kreg[2];
    float  vreg[8];
#pragma unroll
    for (int i = 0; i < 2; ++i) kreg[i] = kptr[i];
#pragma unroll
    for (int r = 0; r < 8; ++r) vreg[r] = vptr[r * 64];

    auto stage = [&](int buf) {
        uint4 u0 = make_uint4(pk2(kreg[0].x, kreg[0].y), pk2(kreg[0].z, kreg[0].w),
                              pk2(kreg[1].x, kreg[1].y), pk2(kreg[1].z, kreg[1].w));
        *(uint4*)&Ks[kh][buf][skey * KSTR + sc * 8] = u0;
        uint4 v0 = make_uint4(pk2(vreg[0], vreg[1]), pk2(vreg[2], vreg[3]),
                              pk2(vreg[4], vreg[5]), pk2(vreg[6], vreg[7]));
        *(uint4*)&Vt[kh][buf][lane * KSTR + wl * 8] = v0;
    };

    stage(0);
    __syncthreads();

    for (int t = 0; t < NTH; ++t) {
        const int cur = t & 1;

        // ---- prefetch next tile into regs (latency hidden under compute) ----
        if (t + 1 < NTH) {
            const float4* kn = kptr + (size_t)(t + 1) * (TK * 16);
#pragma unroll
            for (int i = 0; i < 2; ++i) kreg[i] = kn[i];
            const float* vn = vptr + (size_t)(t + 1) * (TK * D_LEN);
#pragma unroll
            for (int r = 0; r < 8; ++r) vreg[r] = vn[r * 64];
        }

        // ---- fused: S^T = K.Q^T, exp2, in-register P -> O^T += V^T.P^T ----
#pragma unroll
        for (int kt = 0; kt < 2; ++kt) {
            f32x16 s;
#pragma unroll
            for (int i = 0; i < 16; ++i) s[i] = 0.f;
#pragma unroll
            for (int kf = 0; kf < 4; ++kf) {
                bf16x8 ka = *(const bf16x8*)&Ks[kh][cur][(kt * 32 + q31) * KSTR + kf * 16 + hi * 8];
                s = __builtin_amdgcn_mfma_f32_32x32x16_bf16(ka, qf[kf], s, 0, 0, 0);
            }
            // lane holds keys kt*32 + g*8 + hi*4 + (0..3) as s[4g+d], q = q31
#pragma unroll
            for (int f = 0; f < 2; ++f) {
                const int b = f * 8;
                float p0 = FAST_EXP2(s[b + 0]), p1 = FAST_EXP2(s[b + 1]);
                float p2 = FAST_EXP2(s[b + 2]), p3 = FAST_EXP2(s[b + 3]);
                float p4 = FAST_EXP2(s[b + 4]), p5 = FAST_EXP2(s[b + 5]);
                float p6 = FAST_EXP2(s[b + 6]), p7 = FAST_EXP2(s[b + 7]);
                lsum += ((p0 + p1) + (p2 + p3)) + ((p4 + p5) + (p6 + p7));
                unsigned a0 = pk2(p0, p1), a1 = pk2(p4, p5);
                unsigned b0 = pk2(p2, p3), b1 = pk2(p6, p7);
                pl32(a0, a1);
                pl32(b0, b1);
                uint4 u = make_uint4(a0, b0, a1, b1);
                bf16x8 pb = __builtin_bit_cast(bf16x8, u);
                const int kq = kt * 2 + f;
                bf16x8 va0 = *(const bf16x8*)&Vt[kh][cur][q31 * KSTR + kq * 16 + hi * 8];
                bf16x8 va1 = *(const bf16x8*)&Vt[kh][cur][(32 + q31) * KSTR + kq * 16 + hi * 8];
                o0 = __builtin_amdgcn_mfma_f32_32x32x16_bf16(va0, pb, o0, 0, 0, 0);
                o1 = __builtin_amdgcn_mfma_f32_32x32x16_bf16(va1, pb, o1, 0, 0, 0);
            }
        }

        // ---- stage next tile into the other buffer; single barrier ----
        if (t + 1 < NTH) {
            stage(cur ^ 1);
            __syncthreads();
        }
    }

    // ---- epilogue: in-LDS split-K combine (exact: no max-subtraction) ----
    // Per-lane full row-sum for this half: lanes l and l^32 both hold it.
    float l = lsum + __shfl_xor(lsum, 32);

    __syncthreads();   // all tile reads done before overlaying Ks/Vt

    // Exchange buffers overlay the tile memory (both 36,864 B >= 32 KB used).
    // Layout [i][w*64+lane]: lane-minor -> conflict-free.
    float* xo0 = (float*)&Ks[0][0][0];           // o0 partials: 8192 floats
    float* xo1 = (float*)&Vt[0][0][0];           // o1 partials: 8192 floats
    float* xl  = xo0 + 8192;                     // lsum partials: 512 floats

    if (kh == 1) {
#pragma unroll
        for (int i = 0; i < 16; ++i) {
            xo0[(i << 9) | (wl << 6) | lane] = o0[i];
            xo1[(i << 9) | (wl << 6) | lane] = o1[i];
        }
        xl[(wl << 6) | lane] = l;
    }
    __syncthreads();

    if (kh == 0) {
#pragma unroll
        for (int i = 0; i < 16; ++i) {
            o0[i] += xo0[(i << 9) | (wl << 6) | lane];
            o1[i] += xo1[(i << 9) | (wl << 6) | lane];
        }
        const float inv = 1.0f / (l + xl[(wl << 6) | lane]);
        float* ob = og + ((size_t)bh * S_LEN + qrow0 + q31) * D_LEN;
#pragma unroll
        for (int g = 0; g < 4; ++g) {
            float4 f0 = make_float4(o0[4 * g + 0] * inv, o0[4 * g + 1] * inv,
                                    o0[4 * g + 2] * inv, o0[4 * g + 3] * inv);
            ((float4*)(ob + g * 8 + hi * 4))[0] = f0;          // d = 8g + 4hi
            float4 f1 = make_float4(o1[4 * g + 0] * inv, o1[4 * g + 1] * inv,
                                    o1[4 * g + 2] * inv, o1[4 * g + 3] * inv);
            ((float4*)(ob + 32 + g * 8 + hi * 4))[0] = f1;     // d = 32 + 8g + 4hi
        }
    }
}

extern "C" void kernel_launch(void* const* d_in, const int* in_sizes, int n_in,
                              void* d_out, int out_size, void* d_ws, size_t ws_size,
                              hipStream_t stream)
{
    const float* q = (const float*)d_in[0];
    const float* k = (const float*)d_in[1];
    const float* v = (const float*)d_in[2];
    float* out = (float*)d_out;

    dim3 grid(64 * (S_LEN / QT));   // 512 blocks = 2/CU, 32 waves/CU
    dim3 block(THREADS);
    attn_mfma32<<<grid, block, 0, stream>>>(q, k, v, out);
}

// Round 18
// 195.269 us; speedup vs baseline: 4.5097x; 4.5097x over previous
//
#include <hip/hip_runtime.h>

// B=4,H=16,S=2048,D=64 fp32 attention, bf16-MFMA flash kernel, round 24.
// r22 post-mortem: split-K x2 via __launch_bounds__(1024,8) SPILLED --
// 8 waves/EU = 64-reg/wave budget on the unified VGPR/AGPR file; kernel
// needs ~128 (r17: 64 arch + 32 acc). Compiler emitted 32+32 and spilled
// (VGPR=32, WRITE 1.79GB, 804us). Occupancy hit 80% and bought nothing.
// LESSON: 16 waves/CU is a REGISTER ceiling (~128 regs/wave => 4/SIMD),
// not a decomposition limit. Thin-wave (32q x 32d) would cost 1.5x MFMA.
// This round continues the axis that measured wins: per-CU serialization.
//   TK 64 -> 128: halves tile count (32->16) => halves barrier convoys
//   per block (31->15) and loop/prefetch overhead instances, amortizing
//   staging over 2x compute per phase. (r11->r17 won 9% on this axis.)
//   * LDS: Ks 2x128x72hw (36,864B) + Vt 2x64x136hw (34,816B) = 71,680B
//     per block; 2 blocks/CU = 143KB <= 160KB -> occupancy unchanged.
//   * V row stride VSTR=136hw (272B == 4 dwords mod 32 banks): identical
//     free-2-way bank pattern as r17's measured-zero-conflict KSTR=72.
//   * inner loop = r17 verbatim, 4 kt-subtiles (kt 0..3, kq 0..7).
//   * staging: K 4 threads/key (16 d each, 4 float4 -> 2 uint4 writes);
//     V wave wl covers keys wl*16..wl*16+15 (16 scalars -> 2 uint4).
//   * __launch_bounds__(512,4): 128-reg budget (r17-proven, no spill).
// Layouts (m74/m101-verified): A/B frag [i=lane&31][k=(lane>>5)*8+j],
// C/D: col=lane&31, row=(reg&3)+8*(reg>>2)+4*(lane>>5).
// permlane32_swap recipe (m214v22): A=swap(pk2(p0,p1),pk2(p4,p5)),
// B=swap(pk2(p2,p3),pk2(p6,p7)), frag={A0,B0,A1,B1}.

#define S_LEN 2048
#define D_LEN 64
#define QT    256
#define TK    128
#define THREADS 512
#define KSTR  72    // K row stride, halfwords (144 B)
#define VSTR  136   // V row stride, halfwords (272 B)
#define NT    (S_LEN / TK)   // 16 tiles

typedef __attribute__((ext_vector_type(8)))  short bf16x8;
typedef __attribute__((ext_vector_type(16))) float f32x16;

#if __has_builtin(__builtin_amdgcn_exp2f)
#define FAST_EXP2(x) __builtin_amdgcn_exp2f(x)
#else
#define FAST_EXP2(x) __expf((x) * 0.69314718055994531f)
#endif

// HW packed f32->bf16: D[15:0]=bf16(a), D[31:16]=bf16(b). One VALU op.
__device__ __forceinline__ unsigned pk2(float a, float b) {
    unsigned r;
    asm("v_cvt_pk_bf16_f32 %0, %1, %2" : "=v"(r) : "v"(a), "v"(b));
    return r;
}

// v_permlane32_swap_b32 a, b: swaps a's upper-32-lane half with b's
// lower-32-lane half; both outputs are usable fragment words.
__device__ __forceinline__ void pl32(unsigned& a, unsigned& b) {
    asm("v_permlane32_swap_b32 %0, %1" : "+v"(a), "+v"(b));
}

__global__ __launch_bounds__(THREADS, 4)
void attn_mfma32(const float* __restrict__ qg,
                 const float* __restrict__ kg,
                 const float* __restrict__ vg,
                 float* __restrict__ og)
{
    __shared__ alignas(16) unsigned short Ks[2][TK * KSTR];      // [key][d]
    __shared__ alignas(16) unsigned short Vt[2][D_LEN * VSTR];   // [d][key]

    const int tid  = threadIdx.x;
    const int w    = tid >> 6;          // 0..7
    const int lane = tid & 63;
    const int q31  = lane & 31;
    const int hi   = lane >> 5;

    // XCD swizzle (512 blocks, 512%8==0 bijective): all 8 q-blocks of one
    // bh carry the same (bid&7) -> same XCD -> K/V re-reads hit one L2.
    const int swz   = (blockIdx.x & 7) * 64 + (blockIdx.x >> 3);
    const int bh    = swz >> 3;
    const int qblk  = swz & 7;
    const int qrow0 = qblk * QT + w * 32;

    const float* kbase = kg + (size_t)bh * S_LEN * D_LEN;
    const float* vbase = vg + (size_t)bh * S_LEN * D_LEN;

    // ---- Q fragments: B-operand, lane holds Q[qrow0+q31][kf*16+hi*8+j] ----
    const float c = 0.125f * 1.4426950408889634f;
    bf16x8 qf[4];
    {
        const float* qp = qg + ((size_t)bh * S_LEN + qrow0 + q31) * D_LEN + hi * 8;
#pragma unroll
        for (int kf = 0; kf < 4; ++kf) {
            float4 a = ((const float4*)(qp + kf * 16))[0];
            float4 b = ((const float4*)(qp + kf * 16))[1];
            uint4 u = make_uint4(pk2(a.x * c, a.y * c), pk2(a.z * c, a.w * c),
                                 pk2(b.x * c, b.y * c), pk2(b.z * c, b.w * c));
            qf[kf] = __builtin_bit_cast(bf16x8, u);
        }
    }

    f32x16 o0, o1;
#pragma unroll
    for (int i = 0; i < 16; ++i) { o0[i] = 0.f; o1[i] = 0.f; }
    float lsum = 0.f;

    // ---- staging assignment (512 threads, 128-key tile per block) ----
    // K: thread -> key=tid>>2 (0..127), 16-d chunk sc=tid&3; 4 float4.
    const int skey = tid >> 2;
    const int sc   = tid & 3;
    const float4* kptr = (const float4*)kbase + (size_t)skey * 16 + sc * 4;
    // V: lane = d, wave w covers keys w*16..w*16+15; scalar coalesced loads.
    const float* vptr = vbase + (size_t)(w * 16) * D_LEN + lane;

    float4 kreg[4];
    float  vreg[16];
#pragma unroll
    for (int i = 0; i < 4; ++i) kreg[i] = kptr[i];
#pragma unroll
    for (int r = 0; r < 16; ++r) vreg[r] = vptr[r * 64];

    auto stage = [&](int buf) {
        uint4 u0 = make_uint4(pk2(kreg[0].x, kreg[0].y), pk2(kreg[0].z, kreg[0].w),
                              pk2(kreg[1].x, kreg[1].y), pk2(kreg[1].z, kreg[1].w));
        uint4 u1 = make_uint4(pk2(kreg[2].x, kreg[2].y), pk2(kreg[2].z, kreg[2].w),
                              pk2(kreg[3].x, kreg[3].y), pk2(kreg[3].z, kreg[3].w));
        *(uint4*)&Ks[buf][skey * KSTR + sc * 16]     = u0;
        *(uint4*)&Ks[buf][skey * KSTR + sc * 16 + 8] = u1;
        uint4 v0 = make_uint4(pk2(vreg[0], vreg[1]),   pk2(vreg[2], vreg[3]),
                              pk2(vreg[4], vreg[5]),   pk2(vreg[6], vreg[7]));
        uint4 v1 = make_uint4(pk2(vreg[8], vreg[9]),   pk2(vreg[10], vreg[11]),
                              pk2(vreg[12], vreg[13]), pk2(vreg[14], vreg[15]));
        *(uint4*)&Vt[buf][lane * VSTR + w * 16]     = v0;
        *(uint4*)&Vt[buf][lane * VSTR + w * 16 + 8] = v1;
    };

    stage(0);
    __syncthreads();

    for (int t = 0; t < NT; ++t) {
        const int cur = t & 1;

        // ---- prefetch next tile into regs (latency hidden under compute) ----
        if (t + 1 < NT) {
            const float4* kn = kptr + (size_t)(t + 1) * (TK * 16);
#pragma unroll
            for (int i = 0; i < 4; ++i) kreg[i] = kn[i];
            const float* vn = vptr + (size_t)(t + 1) * (TK * D_LEN);
#pragma unroll
            for (int r = 0; r < 16; ++r) vreg[r] = vn[r * 64];
        }

        // ---- fused: S^T = K.Q^T, exp2, in-register P -> O^T += V^T.P^T ----
#pragma unroll
        for (int kt = 0; kt < 4; ++kt) {
            f32x16 s;
#pragma unroll
            for (int i = 0; i < 16; ++i) s[i] = 0.f;
#pragma unroll
            for (int kf = 0; kf < 4; ++kf) {
                bf16x8 ka = *(const bf16x8*)&Ks[cur][(kt * 32 + q31) * KSTR + kf * 16 + hi * 8];
                s = __builtin_amdgcn_mfma_f32_32x32x16_bf16(ka, qf[kf], s, 0, 0, 0);
            }
            // lane holds keys kt*32 + g*8 + hi*4 + (0..3) as s[4g+d], q = q31
#pragma unroll
            for (int f = 0; f < 2; ++f) {
                const int b = f * 8;
                float p0 = FAST_EXP2(s[b + 0]), p1 = FAST_EXP2(s[b + 1]);
                float p2 = FAST_EXP2(s[b + 2]), p3 = FAST_EXP2(s[b + 3]);
                float p4 = FAST_EXP2(s[b + 4]), p5 = FAST_EXP2(s[b + 5]);
                float p6 = FAST_EXP2(s[b + 6]), p7 = FAST_EXP2(s[b + 7]);
                lsum += ((p0 + p1) + (p2 + p3)) + ((p4 + p5) + (p6 + p7));
                unsigned a0 = pk2(p0, p1), a1 = pk2(p4, p5);
                unsigned b0 = pk2(p2, p3), b1 = pk2(p6, p7);
                pl32(a0, a1);
                pl32(b0, b1);
                uint4 u = make_uint4(a0, b0, a1, b1);
                bf16x8 pb = __builtin_bit_cast(bf16x8, u);
                const int kq = kt * 2 + f;
                bf16x8 va0 = *(const bf16x8*)&Vt[cur][q31 * VSTR + kq * 16 + hi * 8];
                bf16x8 va1 = *(const bf16x8*)&Vt[cur][(32 + q31) * VSTR + kq * 16 + hi * 8];
                o0 = __builtin_amdgcn_mfma_f32_32x32x16_bf16(va0, pb, o0, 0, 0, 0);
                o1 = __builtin_amdgcn_mfma_f32_32x32x16_bf16(va1, pb, o1, 0, 0, 0);
            }
        }

        // ---- stage next tile into the other buffer; single barrier ----
        if (t + 1 < NT) {
            stage(cur ^ 1);
            __syncthreads();
        }
    }

    // ---- epilogue ----
    float l = lsum + __shfl_xor(lsum, 32);
    const float inv = 1.0f / l;
    float* ob = og + ((size_t)bh * S_LEN + qrow0 + q31) * D_LEN;
#pragma unroll
    for (int g = 0; g < 4; ++g) {
        float4 f0 = make_float4(o0[4 * g + 0] * inv, o0[4 * g + 1] * inv,
                                o0[4 * g + 2] * inv, o0[4 * g + 3] * inv);
        ((float4*)(ob + g * 8 + hi * 4))[0] = f0;              // d = 8g + 4hi
        float4 f1 = make_float4(o1[4 * g + 0] * inv, o1[4 * g + 1] * inv,
                                o1[4 * g + 2] * inv, o1[4 * g + 3] * inv);
        ((float4*)(ob + 32 + g * 8 + hi * 4))[0] = f1;         // d = 32 + 8g + 4hi
    }
}

extern "C" void kernel_launch(void* const* d_in, const int* in_sizes, int n_in,
                              void* d_out, int out_size, void* d_ws, size_t ws_size,
                              hipStream_t stream)
{
    const float* q = (const float*)d_in[0];
    const float* k = (const float*)d_in[1];
    const float* v = (const float*)d_in[2];
    float* out = (float*)d_out;

    dim3 grid(64 * (S_LEN / QT));   // 512 blocks = 2/CU, 16 waves/CU
    dim3 block(THREADS);
    attn_mfma32<<<grid, block, 0, stream>>>(q, k, v, out);
}

// Round 23
// 187.312 us; speedup vs baseline: 4.7012x; 1.0425x over previous
//
#include <hip/hip_runtime.h>

// B=4,H=16,S=2048,D=64 fp32 attention, bf16-MFMA flash kernel, round 29
// (= round 26 resubmitted verbatim; r26/r27/r28 all hit
//  GPUAcquisitionTimeout before executing -- no counters, no update).
// r25 post-mortem: write-early staging FAILED correctness (absmax 0.067 vs
// 0.0085) -- the reorder created a WAR window between stage()'s in-queue
// ds_writes reading kreg/vreg and loadtile(t+2)'s async VMEM write-back
// re-targeting the same registers (r24's ordering had ~400cy of MFMA
// between load-return and stage-consume; r25 had none). Mechanism not
// fully pinned -> whole reorder disqualified. REVERTED to r24 verbatim
// (measured 99.0us, passed).
// This round's single delta: T5 s_setprio(1) around the fused compute
// region (QK MFMA -> softmax -> PV MFMA), prio 0 for stage/prefetch.
// Between barriers the 8 waves skew (some staging, some in MFMA);
// setprio biases the CU scheduler toward MFMA waves (m191 attn +4-7%,
// m218b: helps when wave roles diverge).
// Lineage: r11 118us -> r17 (8-wave QT=256) 108us -> r24 (TK=128) 99us.
// Occupancy pinned at 16 waves/CU by ~128-reg footprint (r22 spill
// lesson); TK maxed at 143KB/CU LDS; schedule permutations (r12/r16
// pipeline, r25 write-early) regressed or raced.
// Layouts (m74/m101-verified): A/B frag [i=lane&31][k=(lane>>5)*8+j],
// C/D: col=lane&31, row=(reg&3)+8*(reg>>2)+4*(lane>>5).
// permlane32_swap recipe (m214v22): A=swap(pk2(p0,p1),pk2(p4,p5)),
// B=swap(pk2(p2,p3),pk2(p6,p7)), frag={A0,B0,A1,B1}.

#define S_LEN 2048
#define D_LEN 64
#define QT    256
#define TK    128
#define THREADS 512
#define KSTR  72    // K row stride, halfwords (144 B)
#define VSTR  136   // V row stride, halfwords (272 B)
#define NT    (S_LEN / TK)   // 16 tiles

typedef __attribute__((ext_vector_type(8)))  short bf16x8;
typedef __attribute__((ext_vector_type(16))) float f32x16;

#if __has_builtin(__builtin_amdgcn_exp2f)
#define FAST_EXP2(x) __builtin_amdgcn_exp2f(x)
#else
#define FAST_EXP2(x) __expf((x) * 0.69314718055994531f)
#endif

// HW packed f32->bf16: D[15:0]=bf16(a), D[31:16]=bf16(b). One VALU op.
__device__ __forceinline__ unsigned pk2(float a, float b) {
    unsigned r;
    asm("v_cvt_pk_bf16_f32 %0, %1, %2" : "=v"(r) : "v"(a), "v"(b));
    return r;
}

// v_permlane32_swap_b32 a, b: swaps a's upper-32-lane half with b's
// lower-32-lane half; both outputs are usable fragment words.
__device__ __forceinline__ void pl32(unsigned& a, unsigned& b) {
    asm("v_permlane32_swap_b32 %0, %1" : "+v"(a), "+v"(b));
}

__global__ __launch_bounds__(THREADS, 4)
void attn_mfma32(const float* __restrict__ qg,
                 const float* __restrict__ kg,
                 const float* __restrict__ vg,
                 float* __restrict__ og)
{
    __shared__ alignas(16) unsigned short Ks[2][TK * KSTR];      // [key][d]
    __shared__ alignas(16) unsigned short Vt[2][D_LEN * VSTR];   // [d][key]

    const int tid  = threadIdx.x;
    const int w    = tid >> 6;          // 0..7
    const int lane = tid & 63;
    const int q31  = lane & 31;
    const int hi   = lane >> 5;

    // XCD swizzle (512 blocks, 512%8==0 bijective): all 8 q-blocks of one
    // bh carry the same (bid&7) -> same XCD -> K/V re-reads hit one L2.
    const int swz   = (blockIdx.x & 7) * 64 + (blockIdx.x >> 3);
    const int bh    = swz >> 3;
    const int qblk  = swz & 7;
    const int qrow0 = qblk * QT + w * 32;

    const float* kbase = kg + (size_t)bh * S_LEN * D_LEN;
    const float* vbase = vg + (size_t)bh * S_LEN * D_LEN;

    // ---- Q fragments: B-operand, lane holds Q[qrow0+q31][kf*16+hi*8+j] ----
    const float c = 0.125f * 1.4426950408889634f;
    bf16x8 qf[4];
    {
        const float* qp = qg + ((size_t)bh * S_LEN + qrow0 + q31) * D_LEN + hi * 8;
#pragma unroll
        for (int kf = 0; kf < 4; ++kf) {
            float4 a = ((const float4*)(qp + kf * 16))[0];
            float4 b = ((const float4*)(qp + kf * 16))[1];
            uint4 u = make_uint4(pk2(a.x * c, a.y * c), pk2(a.z * c, a.w * c),
                                 pk2(b.x * c, b.y * c), pk2(b.z * c, b.w * c));
            qf[kf] = __builtin_bit_cast(bf16x8, u);
        }
    }

    f32x16 o0, o1;
#pragma unroll
    for (int i = 0; i < 16; ++i) { o0[i] = 0.f; o1[i] = 0.f; }
    float lsum = 0.f;

    // ---- staging assignment (512 threads, 128-key tile per block) ----
    // K: thread -> key=tid>>2 (0..127), 16-d chunk sc=tid&3; 4 float4.
    const int skey = tid >> 2;
    const int sc   = tid & 3;
    const float4* kptr = (const float4*)kbase + (size_t)skey * 16 + sc * 4;
    // V: lane = d, wave w covers keys w*16..w*16+15; scalar coalesced loads.
    const float* vptr = vbase + (size_t)(w * 16) * D_LEN + lane;

    float4 kreg[4];
    float  vreg[16];
#pragma unroll
    for (int i = 0; i < 4; ++i) kreg[i] = kptr[i];
#pragma unroll
    for (int r = 0; r < 16; ++r) vreg[r] = vptr[r * 64];

    auto stage = [&](int buf) {
        uint4 u0 = make_uint4(pk2(kreg[0].x, kreg[0].y), pk2(kreg[0].z, kreg[0].w),
                              pk2(kreg[1].x, kreg[1].y), pk2(kreg[1].z, kreg[1].w));
        uint4 u1 = make_uint4(pk2(kreg[2].x, kreg[2].y), pk2(kreg[2].z, kreg[2].w),
                              pk2(kreg[3].x, kreg[3].y), pk2(kreg[3].z, kreg[3].w));
        *(uint4*)&Ks[buf][skey * KSTR + sc * 16]     = u0;
        *(uint4*)&Ks[buf][skey * KSTR + sc * 16 + 8] = u1;
        uint4 v0 = make_uint4(pk2(vreg[0], vreg[1]),   pk2(vreg[2], vreg[3]),
                              pk2(vreg[4], vreg[5]),   pk2(vreg[6], vreg[7]));
        uint4 v1 = make_uint4(pk2(vreg[8], vreg[9]),   pk2(vreg[10], vreg[11]),
                              pk2(vreg[12], vreg[13]), pk2(vreg[14], vreg[15]));
        *(uint4*)&Vt[buf][lane * VSTR + w * 16]     = v0;
        *(uint4*)&Vt[buf][lane * VSTR + w * 16 + 8] = v1;
    };

    stage(0);
    __syncthreads();

    for (int t = 0; t < NT; ++t) {
        const int cur = t & 1;

        // ---- prefetch next tile into regs (latency hidden under compute) ----
        if (t + 1 < NT) {
            const float4* kn = kptr + (size_t)(t + 1) * (TK * 16);
#pragma unroll
            for (int i = 0; i < 4; ++i) kreg[i] = kn[i];
            const float* vn = vptr + (size_t)(t + 1) * (TK * D_LEN);
#pragma unroll
            for (int r = 0; r < 16; ++r) vreg[r] = vn[r * 64];
        }

        // ---- fused compute at raised priority: waves in this region win
        //      CU-scheduler arbitration over waves still staging (T5) ----
        __builtin_amdgcn_s_setprio(1);
#pragma unroll
        for (int kt = 0; kt < 4; ++kt) {
            f32x16 s;
#pragma unroll
            for (int i = 0; i < 16; ++i) s[i] = 0.f;
#pragma unroll
            for (int kf = 0; kf < 4; ++kf) {
                bf16x8 ka = *(const bf16x8*)&Ks[cur][(kt * 32 + q31) * KSTR + kf * 16 + hi * 8];
                s = __builtin_amdgcn_mfma_f32_32x32x16_bf16(ka, qf[kf], s, 0, 0, 0);
            }
            // lane holds keys kt*32 + g*8 + hi*4 + (0..3) as s[4g+d], q = q31
#pragma unroll
            for (int f = 0; f < 2; ++f) {
                const int b = f * 8;
                float p0 = FAST_EXP2(s[b + 0]), p1 = FAST_EXP2(s[b + 1]);
                float p2 = FAST_EXP2(s[b + 2]), p3 = FAST_EXP2(s[b + 3]);
                float p4 = FAST_EXP2(s[b + 4]), p5 = FAST_EXP2(s[b + 5]);
                float p6 = FAST_EXP2(s[b + 6]), p7 = FAST_EXP2(s[b + 7]);
                lsum += ((p0 + p1) + (p2 + p3)) + ((p4 + p5) + (p6 + p7));
                unsigned a0 = pk2(p0, p1), a1 = pk2(p4, p5);
                unsigned b0 = pk2(p2, p3), b1 = pk2(p6, p7);
                pl32(a0, a1);
                pl32(b0, b1);
                uint4 u = make_uint4(a0, b0, a1, b1);
                bf16x8 pb = __builtin_bit_cast(bf16x8, u);
                const int kq = kt * 2 + f;
                bf16x8 va0 = *(const bf16x8*)&Vt[cur][q31 * VSTR + kq * 16 + hi * 8];
                bf16x8 va1 = *(const bf16x8*)&Vt[cur][(32 + q31) * VSTR + kq * 16 + hi * 8];
                o0 = __builtin_amdgcn_mfma_f32_32x32x16_bf16(va0, pb, o0, 0, 0, 0);
                o1 = __builtin_amdgcn_mfma_f32_32x32x16_bf16(va1, pb, o1, 0, 0, 0);
            }
        }
        __builtin_amdgcn_s_setprio(0);

        // ---- stage next tile into the other buffer; single barrier ----
        if (t + 1 < NT) {
            stage(cur ^ 1);
            __syncthreads();
        }
    }

    // ---- epilogue ----
    float l = lsum + __shfl_xor(lsum, 32);
    const float inv = 1.0f / l;
    float* ob = og + ((size_t)bh * S_LEN + qrow0 + q31) * D_LEN;
#pragma unroll
    for (int g = 0; g < 4; ++g) {
        float4 f0 = make_float4(o0[4 * g + 0] * inv, o0[4 * g + 1] * inv,
                                o0[4 * g + 2] * inv, o0[4 * g + 3] * inv);
        ((float4*)(ob + g * 8 + hi * 4))[0] = f0;              // d = 8g + 4hi
        float4 f1 = make_float4(o1[4 * g + 0] * inv, o1[4 * g + 1] * inv,
                                o1[4 * g + 2] * inv, o1[4 * g + 3] * inv);
        ((float4*)(ob + 32 + g * 8 + hi * 4))[0] = f1;         // d = 32 + 8g + 4hi
    }
}

extern "C" void kernel_launch(void* const* d_in, const int* in_sizes, int n_in,
                              void* d_out, int out_size, void* d_ws, size_t ws_size,
                              hipStream_t stream)
{
    const float* q = (const float*)d_in[0];
    const float* k = (const float*)d_in[1];
    const float* v = (const float*)d_in[2];
    float* out = (float*)d_out;

    dim3 grid(64 * (S_LEN / QT));   // 512 blocks = 2/CU, 16 waves/CU
    dim3 block(THREADS);
    attn_mfma32<<<grid, block, 0, stream>>>(q, k, v, out);
}

// Round 25
// 184.675 us; speedup vs baseline: 4.7684x; 1.0143x over previous
//
#include <hip/hip_runtime.h>

// B=4,H=16,S=2048,D=64 fp32 attention, bf16-MFMA flash kernel, round 31
// (= round 30 resubmitted verbatim; r30 hit GPUAcquisitionTimeout before
//  executing -- no counters, nothing to update on).
// r26 post-mortem: setprio WIN, 99.0 -> 95.5us (predicted 94-99; m191's
// +4-7% attn mechanism confirmed). Lineage: r11 118 -> r17 108 -> r24 99
// -> r26 95.5. Counters: Mfma 31 / VALU 38 / HBM 11% -> still
// serialization-bound, not rooflined.
// This round: the staging-amortization axis's LAST notch -- QT=512,
// 1024-thread blocks, grid 256 = exactly 1 block/CU.
//   * total staging work (global loads, pk2 converts, ds_writes) HALVES
//     again: each K/V tile staged by 4 q-blocks instead of 8.
//   * per-CU barrier convoys halve (one 16-wave convoy vs two 8-wave).
//   * same 16 waves/CU, same 71,680B LDS/block, same 128-reg budget
//     (__launch_bounds__(1024,4) == 4 waves/EU, as r24/r26 proved clean).
//   * inner loop + KSTR/VSTR bank geometry + setprio = r26 verbatim.
//   * RISK (pre-committed): 1 block/CU removes inter-block overlap of the
//     stage-tail/barrier drain; if that bubble > halved staging, revert
//     to r26 and declare plateau (~95us).
// Occupancy ceiling recap (r22): ~128 regs/wave => 4 waves/SIMD; LDS
// 71.7KB => the 16-wave/CU ceiling is joint register+LDS, immovable.
// Layouts (m74/m101-verified): A/B frag [i=lane&31][k=(lane>>5)*8+j],
// C/D: col=lane&31, row=(reg&3)+8*(reg>>2)+4*(lane>>5).
// permlane32_swap recipe (m214v22): A=swap(pk2(p0,p1),pk2(p4,p5)),
// B=swap(pk2(p2,p3),pk2(p6,p7)), frag={A0,B0,A1,B1}.

#define S_LEN 2048
#define D_LEN 64
#define QT    512
#define TK    128
#define THREADS 1024
#define KSTR  72    // K row stride, halfwords (144 B)
#define VSTR  136   // V row stride, halfwords (272 B)
#define NT    (S_LEN / TK)   // 16 tiles

typedef __attribute__((ext_vector_type(8)))  short bf16x8;
typedef __attribute__((ext_vector_type(16))) float f32x16;

#if __has_builtin(__builtin_amdgcn_exp2f)
#define FAST_EXP2(x) __builtin_amdgcn_exp2f(x)
#else
#define FAST_EXP2(x) __expf((x) * 0.69314718055994531f)
#endif

// HW packed f32->bf16: D[15:0]=bf16(a), D[31:16]=bf16(b). One VALU op.
__device__ __forceinline__ unsigned pk2(float a, float b) {
    unsigned r;
    asm("v_cvt_pk_bf16_f32 %0, %1, %2" : "=v"(r) : "v"(a), "v"(b));
    return r;
}

// v_permlane32_swap_b32 a, b: swaps a's upper-32-lane half with b's
// lower-32-lane half; both outputs are usable fragment words.
__device__ __forceinline__ void pl32(unsigned& a, unsigned& b) {
    asm("v_permlane32_swap_b32 %0, %1" : "+v"(a), "+v"(b));
}

__global__ __launch_bounds__(THREADS, 4)
void attn_mfma32(const float* __restrict__ qg,
                 const float* __restrict__ kg,
                 const float* __restrict__ vg,
                 float* __restrict__ og)
{
    __shared__ alignas(16) unsigned short Ks[2][TK * KSTR];      // [key][d]
    __shared__ alignas(16) unsigned short Vt[2][D_LEN * VSTR];   // [d][key]

    const int tid  = threadIdx.x;
    const int w    = tid >> 6;          // 0..15
    const int lane = tid & 63;
    const int q31  = lane & 31;
    const int hi   = lane >> 5;

    // XCD swizzle (256 blocks, 256%8==0 bijective): XCD x gets bh x*8..x*8+7
    // entirely (all 4 q-blocks each) -> K/V 4x-reuse within one L2.
    const int swz   = (blockIdx.x & 7) * 32 + (blockIdx.x >> 3);
    const int bh    = swz >> 2;
    const int qblk  = swz & 3;
    const int qrow0 = qblk * QT + w * 32;

    const float* kbase = kg + (size_t)bh * S_LEN * D_LEN;
    const float* vbase = vg + (size_t)bh * S_LEN * D_LEN;

    // ---- Q fragments: B-operand, lane holds Q[qrow0+q31][kf*16+hi*8+j] ----
    const float c = 0.125f * 1.4426950408889634f;
    bf16x8 qf[4];
    {
        const float* qp = qg + ((size_t)bh * S_LEN + qrow0 + q31) * D_LEN + hi * 8;
#pragma unroll
        for (int kf = 0; kf < 4; ++kf) {
            float4 a = ((const float4*)(qp + kf * 16))[0];
            float4 b = ((const float4*)(qp + kf * 16))[1];
            uint4 u = make_uint4(pk2(a.x * c, a.y * c), pk2(a.z * c, a.w * c),
                                 pk2(b.x * c, b.y * c), pk2(b.z * c, b.w * c));
            qf[kf] = __builtin_bit_cast(bf16x8, u);
        }
    }

    f32x16 o0, o1;
#pragma unroll
    for (int i = 0; i < 16; ++i) { o0[i] = 0.f; o1[i] = 0.f; }
    float lsum = 0.f;

    // ---- staging assignment (1024 threads, one 128-key tile per block) ----
    // K: thread -> key=tid>>3 (0..127), 8-d chunk sc=tid&7; 2 float4.
    const int skey = tid >> 3;
    const int sc   = tid & 7;
    const float* kp0 = kbase + (size_t)skey * D_LEN + sc * 8;
    // V: lane = d, wave w covers keys w*8..w*8+7; scalar coalesced loads.
    const float* vptr = vbase + (size_t)(w * 8) * D_LEN + lane;

    float4 kreg[2];
    float  vreg[8];
#pragma unroll
    for (int i = 0; i < 2; ++i) kreg[i] = ((const float4*)kp0)[i];
#pragma unroll
    for (int r = 0; r < 8; ++r) vreg[r] = vptr[r * 64];

    auto stage = [&](int buf) {
        uint4 u0 = make_uint4(pk2(kreg[0].x, kreg[0].y), pk2(kreg[0].z, kreg[0].w),
                              pk2(kreg[1].x, kreg[1].y), pk2(kreg[1].z, kreg[1].w));
        *(uint4*)&Ks[buf][skey * KSTR + sc * 8] = u0;
        uint4 v0 = make_uint4(pk2(vreg[0], vreg[1]), pk2(vreg[2], vreg[3]),
                              pk2(vreg[4], vreg[5]), pk2(vreg[6], vreg[7]));
        *(uint4*)&Vt[buf][lane * VSTR + w * 8] = v0;
    };

    stage(0);
    __syncthreads();

    for (int t = 0; t < NT; ++t) {
        const int cur = t & 1;

        // ---- prefetch next tile into regs (latency hidden under compute) ----
        if (t + 1 < NT) {
            const float4* kn = (const float4*)(kp0 + (size_t)(t + 1) * (TK * D_LEN));
#pragma unroll
            for (int i = 0; i < 2; ++i) kreg[i] = kn[i];
            const float* vn = vptr + (size_t)(t + 1) * (TK * D_LEN);
#pragma unroll
            for (int r = 0; r < 8; ++r) vreg[r] = vn[r * 64];
        }

        // ---- fused compute at raised priority (T5, r26-measured +3.5%) ----
        __builtin_amdgcn_s_setprio(1);
#pragma unroll
        for (int kt = 0; kt < 4; ++kt) {
            f32x16 s;
#pragma unroll
            for (int i = 0; i < 16; ++i) s[i] = 0.f;
#pragma unroll
            for (int kf = 0; kf < 4; ++kf) {
                bf16x8 ka = *(const bf16x8*)&Ks[cur][(kt * 32 + q31) * KSTR + kf * 16 + hi * 8];
                s = __builtin_amdgcn_mfma_f32_32x32x16_bf16(ka, qf[kf], s, 0, 0, 0);
            }
            // lane holds keys kt*32 + g*8 + hi*4 + (0..3) as s[4g+d], q = q31
#pragma unroll
            for (int f = 0; f < 2; ++f) {
                const int b = f * 8;
                float p0 = FAST_EXP2(s[b + 0]), p1 = FAST_EXP2(s[b + 1]);
                float p2 = FAST_EXP2(s[b + 2]), p3 = FAST_EXP2(s[b + 3]);
                float p4 = FAST_EXP2(s[b + 4]), p5 = FAST_EXP2(s[b + 5]);
                float p6 = FAST_EXP2(s[b + 6]), p7 = FAST_EXP2(s[b + 7]);
                lsum += ((p0 + p1) + (p2 + p3)) + ((p4 + p5) + (p6 + p7));
                unsigned a0 = pk2(p0, p1), a1 = pk2(p4, p5);
                unsigned b0 = pk2(p2, p3), b1 = pk2(p6, p7);
                pl32(a0, a1);
                pl32(b0, b1);
                uint4 u = make_uint4(a0, b0, a1, b1);
                bf16x8 pb = __builtin_bit_cast(bf16x8, u);
                const int kq = kt * 2 + f;
                bf16x8 va0 = *(const bf16x8*)&Vt[cur][q31 * VSTR + kq * 16 + hi * 8];
                bf16x8 va1 = *(const bf16x8*)&Vt[cur][(32 + q31) * VSTR + kq * 16 + hi * 8];
                o0 = __builtin_amdgcn_mfma_f32_32x32x16_bf16(va0, pb, o0, 0, 0, 0);
                o1 = __builtin_amdgcn_mfma_f32_32x32x16_bf16(va1, pb, o1, 0, 0, 0);
            }
        }
        __builtin_amdgcn_s_setprio(0);

        // ---- stage next tile into the other buffer; single barrier ----
        if (t + 1 < NT) {
            stage(cur ^ 1);
            __syncthreads();
        }
    }

    // ---- epilogue ----
    float l = lsum + __shfl_xor(lsum, 32);
    const float inv = 1.0f / l;
    float* ob = og + ((size_t)bh * S_LEN + qrow0 + q31) * D_LEN;
#pragma unroll
    for (int g = 0; g < 4; ++g) {
        float4 f0 = make_float4(o0[4 * g + 0] * inv, o0[4 * g + 1] * inv,
                                o0[4 * g + 2] * inv, o0[4 * g + 3] * inv);
        ((float4*)(ob + g * 8 + hi * 4))[0] = f0;              // d = 8g + 4hi
        float4 f1 = make_float4(o1[4 * g + 0] * inv, o1[4 * g + 1] * inv,
                                o1[4 * g + 2] * inv, o1[4 * g + 3] * inv);
        ((float4*)(ob + 32 + g * 8 + hi * 4))[0] = f1;         // d = 32 + 8g + 4hi
    }
}

extern "C" void kernel_launch(void* const* d_in, const int* in_sizes, int n_in,
                              void* d_out, int out_size, void* d_ws, size_t ws_size,
                              hipStream_t stream)
{
    const float* q = (const float*)d_in[0];
    const float* k = (const float*)d_in[1];
    const float* v = (const float*)d_in[2];
    float* out = (float*)d_out;

    dim3 grid(64 * (S_LEN / QT));   // 256 blocks = 1/CU, 16 waves/CU
    dim3 block(THREADS);
    attn_mfma32<<<grid, block, 0, stream>>>(q, k, v, out);
}

// Round 26
// 183.809 us; speedup vs baseline: 4.7908x; 1.0047x over previous
//
#include <hip/hip_runtime.h>

// B=4,H=16,S=2048,D=64 fp32 attention, bf16-MFMA flash kernel, round 32.
// r30 post-mortem: QT=512 / 1-block-per-CU WIN, 95.5 -> ~90us (predicted
// 88-94). Staging-amortization axis EXHAUSTED (4 wins: 118->108->99->
// 95.5->90). Counters: Mfma 32.5 (= exact 29us FLOP floor / 90us) /
// VALU 37.5 / HBM 12 -> ~30% cycles still stalled; all pipes <=40%.
// VGPR=60 shows compiler keeps ONE s accumulator -> the 4 independent
// kt-subtiles run strictly sequentially; with only 4 waves/SIMD the
// QK accumulator chain + softmax chain latencies are exposed.
// This round: 2-WAY KT-CHAIN INTERLEAVE (pure ILP, no sync changes).
//   * kt-subtiles processed in pairs with named accumulators sa/sb:
//     QK phase issues two independent MFMA chains interleaved (2x
//     MFMA-pipe ILP, half the exposed accumulator latency); sa's
//     softmax (VALU/trans) overlaps sb's in-flight MFMAs.
//   * +16 VGPR for sb (~110 total est., under the 128-reg budget that
//     r24/r26/r30 proved spill-free). Spill signature = WRITE balloon.
//   * geometry/strides/setprio/barriers = r30 verbatim.
// Layouts (m74/m101-verified): A/B frag [i=lane&31][k=(lane>>5)*8+j],
// C/D: col=lane&31, row=(reg&3)+8*(reg>>2)+4*(lane>>5).
// permlane32_swap recipe (m214v22): A=swap(pk2(p0,p1),pk2(p4,p5)),
// B=swap(pk2(p2,p3),pk2(p6,p7)), frag={A0,B0,A1,B1}.

#define S_LEN 2048
#define D_LEN 64
#define QT    512
#define TK    128
#define THREADS 1024
#define KSTR  72    // K row stride, halfwords (144 B)
#define VSTR  136   // V row stride, halfwords (272 B)
#define NT    (S_LEN / TK)   // 16 tiles

typedef __attribute__((ext_vector_type(8)))  short bf16x8;
typedef __attribute__((ext_vector_type(16))) float f32x16;

#if __has_builtin(__builtin_amdgcn_exp2f)
#define FAST_EXP2(x) __builtin_amdgcn_exp2f(x)
#else
#define FAST_EXP2(x) __expf((x) * 0.69314718055994531f)
#endif

// HW packed f32->bf16: D[15:0]=bf16(a), D[31:16]=bf16(b). One VALU op.
__device__ __forceinline__ unsigned pk2(float a, float b) {
    unsigned r;
    asm("v_cvt_pk_bf16_f32 %0, %1, %2" : "=v"(r) : "v"(a), "v"(b));
    return r;
}

// v_permlane32_swap_b32 a, b: swaps a's upper-32-lane half with b's
// lower-32-lane half; both outputs are usable fragment words.
__device__ __forceinline__ void pl32(unsigned& a, unsigned& b) {
    asm("v_permlane32_swap_b32 %0, %1" : "+v"(a), "+v"(b));
}

// softmax + PV for one 8-score block (f) of accumulator S at subtile KT.
#define SMPV(S, KT, F)                                                      \
    {                                                                       \
        const int b = (F) * 8;                                              \
        float p0 = FAST_EXP2(S[b + 0]), p1 = FAST_EXP2(S[b + 1]);           \
        float p2 = FAST_EXP2(S[b + 2]), p3 = FAST_EXP2(S[b + 3]);           \
        float p4 = FAST_EXP2(S[b + 4]), p5 = FAST_EXP2(S[b + 5]);           \
        float p6 = FAST_EXP2(S[b + 6]), p7 = FAST_EXP2(S[b + 7]);           \
        lsum += ((p0 + p1) + (p2 + p3)) + ((p4 + p5) + (p6 + p7));          \
        unsigned a0 = pk2(p0, p1), a1 = pk2(p4, p5);                        \
        unsigned b0 = pk2(p2, p3), b1 = pk2(p6, p7);                        \
        pl32(a0, a1);                                                       \
        pl32(b0, b1);                                                       \
        uint4 u = make_uint4(a0, b0, a1, b1);                               \
        bf16x8 pb = __builtin_bit_cast(bf16x8, u);                          \
        const int kq = (KT) * 2 + (F);                                      \
        bf16x8 va0 = *(const bf16x8*)&Vt[cur][q31 * VSTR + kq * 16 + hi * 8];       \
        bf16x8 va1 = *(const bf16x8*)&Vt[cur][(32 + q31) * VSTR + kq * 16 + hi * 8];\
        o0 = __builtin_amdgcn_mfma_f32_32x32x16_bf16(va0, pb, o0, 0, 0, 0); \
        o1 = __builtin_amdgcn_mfma_f32_32x32x16_bf16(va1, pb, o1, 0, 0, 0); \
    }

__global__ __launch_bounds__(THREADS, 4)
void attn_mfma32(const float* __restrict__ qg,
                 const float* __restrict__ kg,
                 const float* __restrict__ vg,
                 float* __restrict__ og)
{
    __shared__ alignas(16) unsigned short Ks[2][TK * KSTR];      // [key][d]
    __shared__ alignas(16) unsigned short Vt[2][D_LEN * VSTR];   // [d][key]

    const int tid  = threadIdx.x;
    const int w    = tid >> 6;          // 0..15
    const int lane = tid & 63;
    const int q31  = lane & 31;
    const int hi   = lane >> 5;

    // XCD swizzle (256 blocks, 256%8==0 bijective): XCD x gets bh x*8..x*8+7
    // entirely (all 4 q-blocks each) -> K/V 4x-reuse within one L2.
    const int swz   = (blockIdx.x & 7) * 32 + (blockIdx.x >> 3);
    const int bh    = swz >> 2;
    const int qblk  = swz & 3;
    const int qrow0 = qblk * QT + w * 32;

    const float* kbase = kg + (size_t)bh * S_LEN * D_LEN;
    const float* vbase = vg + (size_t)bh * S_LEN * D_LEN;

    // ---- Q fragments: B-operand, lane holds Q[qrow0+q31][kf*16+hi*8+j] ----
    const float c = 0.125f * 1.4426950408889634f;
    bf16x8 qf[4];
    {
        const float* qp = qg + ((size_t)bh * S_LEN + qrow0 + q31) * D_LEN + hi * 8;
#pragma unroll
        for (int kf = 0; kf < 4; ++kf) {
            float4 a = ((const float4*)(qp + kf * 16))[0];
            float4 b = ((const float4*)(qp + kf * 16))[1];
            uint4 u = make_uint4(pk2(a.x * c, a.y * c), pk2(a.z * c, a.w * c),
                                 pk2(b.x * c, b.y * c), pk2(b.z * c, b.w * c));
            qf[kf] = __builtin_bit_cast(bf16x8, u);
        }
    }

    f32x16 o0, o1;
#pragma unroll
    for (int i = 0; i < 16; ++i) { o0[i] = 0.f; o1[i] = 0.f; }
    float lsum = 0.f;

    // ---- staging assignment (1024 threads, one 128-key tile per block) ----
    // K: thread -> key=tid>>3 (0..127), 8-d chunk sc=tid&7; 2 float4.
    const int skey = tid >> 3;
    const int sc   = tid & 7;
    const float* kp0 = kbase + (size_t)skey * D_LEN + sc * 8;
    // V: lane = d, wave w covers keys w*8..w*8+7; scalar coalesced loads.
    const float* vptr = vbase + (size_t)(w * 8) * D_LEN + lane;

    float4 kreg[2];
    float  vreg[8];
#pragma unroll
    for (int i = 0; i < 2; ++i) kreg[i] = ((const float4*)kp0)[i];
#pragma unroll
    for (int r = 0; r < 8; ++r) vreg[r] = vptr[r * 64];

    auto stage = [&](int buf) {
        uint4 u0 = make_uint4(pk2(kreg[0].x, kreg[0].y), pk2(kreg[0].z, kreg[0].w),
                              pk2(kreg[1].x, kreg[1].y), pk2(kreg[1].z, kreg[1].w));
        *(uint4*)&Ks[buf][skey * KSTR + sc * 8] = u0;
        uint4 v0 = make_uint4(pk2(vreg[0], vreg[1]), pk2(vreg[2], vreg[3]),
                              pk2(vreg[4], vreg[5]), pk2(vreg[6], vreg[7]));
        *(uint4*)&Vt[buf][lane * VSTR + w * 8] = v0;
    };

    stage(0);
    __syncthreads();

    for (int t = 0; t < NT; ++t) {
        const int cur = t & 1;

        // ---- prefetch next tile into regs (latency hidden under compute) ----
        if (t + 1 < NT) {
            const float4* kn = (const float4*)(kp0 + (size_t)(t + 1) * (TK * D_LEN));
#pragma unroll
            for (int i = 0; i < 2; ++i) kreg[i] = kn[i];
            const float* vn = vptr + (size_t)(t + 1) * (TK * D_LEN);
#pragma unroll
            for (int r = 0; r < 8; ++r) vreg[r] = vn[r * 64];
        }

        // ---- fused compute at raised priority (T5, r26-measured +3.5%) ----
        // kt-subtiles in PAIRS: two independent QK MFMA chains interleaved
        // (sa/sb), then softmax+PV of each; sb's MFMAs drain under sa's
        // softmax -> intra-wave MFMA||VALU overlap.
        __builtin_amdgcn_s_setprio(1);
#pragma unroll
        for (int kp = 0; kp < 2; ++kp) {
            f32x16 sa, sb;
#pragma unroll
            for (int i = 0; i < 16; ++i) { sa[i] = 0.f; sb[i] = 0.f; }
#pragma unroll
            for (int kf = 0; kf < 4; ++kf) {
                bf16x8 kaa = *(const bf16x8*)&Ks[cur][((kp * 2)     * 32 + q31) * KSTR + kf * 16 + hi * 8];
                bf16x8 kab = *(const bf16x8*)&Ks[cur][((kp * 2 + 1) * 32 + q31) * KSTR + kf * 16 + hi * 8];
                sa = __builtin_amdgcn_mfma_f32_32x32x16_bf16(kaa, qf[kf], sa, 0, 0, 0);
                sb = __builtin_amdgcn_mfma_f32_32x32x16_bf16(kab, qf[kf], sb, 0, 0, 0);
            }
            SMPV(sa, kp * 2,     0)
            SMPV(sa, kp * 2,     1)
            SMPV(sb, kp * 2 + 1, 0)
            SMPV(sb, kp * 2 + 1, 1)
        }
        __builtin_amdgcn_s_setprio(0);

        // ---- stage next tile into the other buffer; single barrier ----
        if (t + 1 < NT) {
            stage(cur ^ 1);
            __syncthreads();
        }
    }

    // ---- epilogue ----
    float l = lsum + __shfl_xor(lsum, 32);
    const float inv = 1.0f / l;
    float* ob = og + ((size_t)bh * S_LEN + qrow0 + q31) * D_LEN;
#pragma unroll
    for (int g = 0; g < 4; ++g) {
        float4 f0 = make_float4(o0[4 * g + 0] * inv, o0[4 * g + 1] * inv,
                                o0[4 * g + 2] * inv, o0[4 * g + 3] * inv);
        ((float4*)(ob + g * 8 + hi * 4))[0] = f0;              // d = 8g + 4hi
        float4 f1 = make_float4(o1[4 * g + 0] * inv, o1[4 * g + 1] * inv,
                                o1[4 * g + 2] * inv, o1[4 * g + 3] * inv);
        ((float4*)(ob + 32 + g * 8 + hi * 4))[0] = f1;         // d = 32 + 8g + 4hi
    }
}

extern "C" void kernel_launch(void* const* d_in, const int* in_sizes, int n_in,
                              void* d_out, int out_size, void* d_ws, size_t ws_size,
                              hipStream_t stream)
{
    const float* q = (const float*)d_in[0];
    const float* k = (const float*)d_in[1];
    const float* v = (const float*)d_in[2];
    float* out = (float*)d_out;

    dim3 grid(64 * (S_LEN / QT));   // 256 blocks = 1/CU, 16 waves/CU
    dim3 block(THREADS);
    attn_mfma32<<<grid, block, 0, stream>>>(q, k, v, out);
}